// Round 1
// baseline (295.974 us; speedup 1.0000x reference)
//
#include <hip/hip_runtime.h>
#include <cmath>

#define D_IN 512
#define HC   512   // H1*C1 == H2*C2 == D_IN
#define NH1  8
#define NC1  64
#define NH2  4
#define NC2  128
#define BM 128
#define BN 128

typedef __attribute__((ext_vector_type(8))) short short8;
typedef __attribute__((ext_vector_type(8))) unsigned short u16x8;
typedef __attribute__((ext_vector_type(4))) float f32x4;

__device__ inline ushort f2bf(float f) {
  unsigned u = __float_as_uint(f);
  return (ushort)((u + 0x7FFFu + ((u >> 16) & 1u)) >> 16);
}
__device__ inline float bf2f(ushort b) { return __uint_as_float(((unsigned)b) << 16); }

// ---------- all input casts in one launch ----------------------------------
__global__ void k_cast_all(const float* __restrict__ x, ushort* __restrict__ Abf,
                           const float* __restrict__ W1, const float* __restrict__ W2,
                           ushort* __restrict__ Wt1, ushort* __restrict__ Wt2, int n4x) {
  const int KN = D_IN * HC;
  int i = blockIdx.x * blockDim.x + threadIdx.x;
  if (i < n4x) {
    float4 v = ((const float4*)x)[i];
    ushort4 r = { f2bf(v.x), f2bf(v.y), f2bf(v.z), f2bf(v.w) };
    ((ushort4*)Abf)[i] = r;
  } else {
    int idx = i - n4x;
    if (idx >= 2 * KN) return;
    const float* W = (idx < KN) ? W1 : W2;
    ushort* Wt = (idx < KN) ? Wt1 : Wt2;
    int j = (idx < KN) ? idx : idx - KN;
    int n = j / D_IN, k = j - n * D_IN;
    Wt[j] = f2bf(W[(size_t)k * HC + n]);
  }
}

// ---------- bf16 MFMA GEMM, 2-phase double-buffered BK=32, fused att -------
// R14: replaced "sync; stage; sync(vmcnt0-drain); compute" with the minimum
// 2-phase pipeline (T3 recipe): issue next K-tile's 4 global_load_lds BEFORE
// compute, then `s_waitcnt vmcnt(4)` (counted — prefetch stays in flight) +
// raw s_barrier. BK=32 double-buffer keeps LDS at 32KB (same occupancy as
// R13 baseline — do NOT trade occupancy for traffic, BN=512 regressed 42->79).
// Fragment layout per 32-col tile identical to old per-half scheme
// (conflict-free, verified R9). XCD-aware bijective swizzle (m204): the 4
// n-blocks sharing an A row-panel land on the same XCD -> A L2-local.
// Att epilogue unchanged: plain stores only. H=8 (C=64): one slot/(row,h).
// H=4 (C=128): two partial slots [(row*4+h)*2+sub], sub=col64-idx.
template<int H>
__global__ void k_gemm_bf16(const ushort* __restrict__ A, const ushort* __restrict__ Bt,
                            ushort* __restrict__ Cbf,
                            const float* __restrict__ att_s, const float* __restrict__ att_d,
                            float* __restrict__ asrc, float* __restrict__ adst, int M) {
  constexpr int C = HC / H;
  __shared__ __align__(16) ushort As[2 * 4096];   // 2 bufs x (128 rows x 32 cols)
  __shared__ __align__(16) ushort Bs[2 * 4096];
  int t = threadIdx.x;

  // bijective XCD swizzle (nwg=628, 8 XCDs): contiguous wg-chunk per XCD
  int nwg = gridDim.x * gridDim.y;
  int lin = blockIdx.y * gridDim.x + blockIdx.x;
  int q = nwg >> 3, r = nwg & 7;
  int xcd = lin & 7, pos = lin >> 3;
  int wg = (xcd < r ? xcd * (q + 1) : r * (q + 1) + (xcd - r) * q) + pos;
  int m0 = (wg >> 2) * BM;        // gridDim.x == 4
  int n0 = (wg & 3) * BN;

  int wave = t >> 6, lane = t & 63;
  int ln = lane & 15, qd = lane >> 4;
  int wm = (wave >> 1) * 64, wn = (wave & 1) * 64;

  f32x4 acc[4][4] = {};

  int g = t >> 6, ct = (t >> 4) & 3, lt = t & 15;
  int rA0 = m0 + g * 16 + lt;      if (rA0 > M - 1) rA0 = M - 1;
  int rA1 = m0 + 64 + g * 16 + lt; if (rA1 > M - 1) rA1 = M - 1;
  const ushort* gA0 = A + (size_t)rA0 * D_IN + ct * 8;
  const ushort* gA1 = A + (size_t)rA1 * D_IN + ct * 8;
  const ushort* gB0 = Bt + (size_t)(n0 + g * 16 + lt) * D_IN + ct * 8;
  const ushort* gB1 = Bt + (size_t)(n0 + 64 + g * 16 + lt) * D_IN + ct * 8;

#define STAGE(buf, ko)                                                          \
  do {                                                                          \
    int lo_ = (buf) * 4096;                                                     \
    __builtin_amdgcn_global_load_lds(                                           \
        (const __attribute__((address_space(1))) void*)(gA0 + (ko)),            \
        (__attribute__((address_space(3))) void*)(As + lo_ + t * 8), 16, 0, 0); \
    __builtin_amdgcn_global_load_lds(                                           \
        (const __attribute__((address_space(1))) void*)(gA1 + (ko)),            \
        (__attribute__((address_space(3))) void*)(As + lo_ + 2048 + t * 8), 16, 0, 0); \
    __builtin_amdgcn_global_load_lds(                                           \
        (const __attribute__((address_space(1))) void*)(gB0 + (ko)),            \
        (__attribute__((address_space(3))) void*)(Bs + lo_ + t * 8), 16, 0, 0); \
    __builtin_amdgcn_global_load_lds(                                           \
        (const __attribute__((address_space(1))) void*)(gB1 + (ko)),            \
        (__attribute__((address_space(3))) void*)(Bs + lo_ + 2048 + t * 8), 16, 0, 0); \
  } while (0)

  STAGE(0, 0);
  int cur = 0;
  for (int it = 0; it < 16; ++it) {
    if (it < 15) {
      STAGE(cur ^ 1, (it + 1) * 32);                 // prefetch next tile
      asm volatile("s_waitcnt vmcnt(4)" ::: "memory"); // current tile landed
    } else {
      asm volatile("s_waitcnt vmcnt(0)" ::: "memory");
    }
    __builtin_amdgcn_s_barrier();                    // raw: no vmcnt(0) drain
    int lo = cur * 4096;
    short8 a[4], bb[4];
#pragma unroll
    for (int i = 0; i < 4; ++i)
      a[i] = *(const short8*)&As[lo + (((wave >> 1) * 4 + i) * 4 + qd) * 128 + ln * 8];
#pragma unroll
    for (int j = 0; j < 4; ++j)
      bb[j] = *(const short8*)&Bs[lo + (((wave & 1) * 4 + j) * 4 + qd) * 128 + ln * 8];
#pragma unroll
    for (int i = 0; i < 4; ++i)
#pragma unroll
      for (int j = 0; j < 4; ++j)
        acc[i][j] = __builtin_amdgcn_mfma_f32_16x16x32_bf16(a[i], bb[j], acc[i][j], 0, 0, 0);
    __builtin_amdgcn_s_barrier();                    // reads done before overwrite
    cur ^= 1;
  }
#undef STAGE

  // ---- C store (C/D layout: col = ln, row = qd*4 + reg) ----
#pragma unroll
  for (int i = 0; i < 4; ++i) {
#pragma unroll
    for (int reg = 0; reg < 4; ++reg) {
      int row = m0 + wm + i * 16 + qd * 4 + reg;
      if (row >= M) continue;
#pragma unroll
      for (int j = 0; j < 4; ++j)
        Cbf[(size_t)row * HC + n0 + wn + j * 16 + ln] = f2bf(acc[i][j][reg]);
    }
  }

  // ---- fused attention scores (plain stores only) ----
  int colbase = n0 + wn;         // multiple of 64
  int h = colbase / C;
  float sa[4], da[4];
#pragma unroll
  for (int j = 0; j < 4; ++j) {
    int c = (colbase % C) + j * 16 + ln;
    sa[j] = att_s[h * C + c];
    da[j] = att_d[h * C + c];
  }
#pragma unroll
  for (int i = 0; i < 4; ++i) {
#pragma unroll
    for (int reg = 0; reg < 4; ++reg) {
      float ps = acc[i][0][reg] * sa[0] + acc[i][1][reg] * sa[1]
               + acc[i][2][reg] * sa[2] + acc[i][3][reg] * sa[3];
      float pd = acc[i][0][reg] * da[0] + acc[i][1][reg] * da[1]
               + acc[i][2][reg] * da[2] + acc[i][3][reg] * da[3];
#pragma unroll
      for (int o = 1; o < 16; o <<= 1) { ps += __shfl_xor(ps, o); pd += __shfl_xor(pd, o); }
      int row = m0 + wm + i * 16 + qd * 4 + reg;
      if (ln == 0 && row < M) {
        if (C == 64) {
          asrc[row * H + h] = ps; adst[row * H + h] = pd;
        } else {
          int sub = (colbase >> 6) & 1;
          asrc[(row * H + h) * 2 + sub] = ps;
          adst[(row * H + h) * 2 + sub] = pd;
        }
      }
    }
  }
}

// ---------------- CSR build ------------------------------------------------
__global__ void k_hist(const int* __restrict__ ei, int E, int Etot, int* __restrict__ cnt) {
  int e = blockIdx.x * blockDim.x + threadIdx.x;
  if (e >= Etot) return;
  int d = (e < E) ? ei[E + e] : e - E;
  atomicAdd(&cnt[d], 1);
}

// single-block scan, thread-serial + shuffle (2 barriers total)
__global__ void k_scan(const int* __restrict__ cnt, int* __restrict__ rowstart, int N) {
  int tid = threadIdx.x;                 // 1024
  int T = (N + 1023) / 1024;
  int base = tid * T;
  int sum = 0;
  for (int i = 0; i < T; ++i) { int j = base + i; if (j < N) sum += cnt[j]; }
  int lane = tid & 63, w = tid >> 6;
  int v = sum;
#pragma unroll
  for (int off = 1; off < 64; off <<= 1) {
    int u = __shfl_up(v, off);
    if (lane >= off) v += u;
  }
  __shared__ int wsum[16];
  if (lane == 63) wsum[w] = v;
  __syncthreads();
  if (tid < 16) {
    int tv = wsum[tid];
#pragma unroll
    for (int off = 1; off < 16; off <<= 1) {
      int u = __shfl_up(tv, off);
      if (tid >= off) tv += u;
    }
    wsum[tid] = tv;
  }
  __syncthreads();
  int wave_prefix = (w == 0) ? 0 : wsum[w - 1];
  int run = wave_prefix + v - sum;       // exclusive prefix for this thread
  for (int i = 0; i < T; ++i) {
    int j = base + i;
    if (j < N) { rowstart[j] = run; run += cnt[j]; }
  }
  if (tid == 1023) rowstart[N] = run;
}

__global__ void k_scatter(const int* __restrict__ ei, int E, int Etot,
                          const int* __restrict__ rowstart, int* __restrict__ cursor,
                          int* __restrict__ csr_src) {
  int e = blockIdx.x * blockDim.x + threadIdx.x;
  if (e >= Etot) return;
  int s = (e < E) ? ei[e] : e - E;
  int d = (e < E) ? ei[E + e] : e - E;
  int pos = atomicAdd(&cursor[d], 1);
  csr_src[rowstart[d] + pos] = s;
}

// -------- gather aggregation, ONE WAVE PER NODE (R14) ----------------------
// R13 version (128 thr/node, LDS edge cache, 2 barriers/chunk, 8B loads) was
// latency-bound: 41.7us, 24% HBM, occ 59%. R14: wave-per-node, 4 nodes per
// 256-thr block (grid/4), no LDS/barriers — edge ids loaded 64-wide and
// broadcast via __shfl; 16B/lane gathers double bytes-in-flight and halve
// instruction count. 2-way edge unroll for MLP. No max-subtraction (scores
// O(1), fp32-safe).
// MODE 1 (H=8): scores at [x*H+h]; hout = bf16(elu(sum/den + b)).
// MODE 2 (H=4): scores are 2 partials at [(x*H+h)*2+{0,1}];
//   head-mean via shfl_xor(16,32) fold; fused CE via 16-lane butterflies.
template<int H, int MODE>
__global__ void k_agg(const int* __restrict__ rowstart, const int* __restrict__ csr_src,
                      const float* __restrict__ asrc, const float* __restrict__ adst,
                      const ushort* __restrict__ xp, ushort* __restrict__ hout,
                      float* __restrict__ out2, const float* __restrict__ bias,
                      const int* __restrict__ y, const int* __restrict__ msk,
                      float* __restrict__ acc2, int N) {
  constexpr int C = HC / H;
  int wv = threadIdx.x >> 6, lane = threadIdx.x & 63;
  int n = blockIdx.x * 4 + wv;
  if (n >= N) return;                         // wave-uniform
  int h = (MODE == 1) ? (lane >> 3) : (lane >> 4);   // 8 chans/lane
  int beg = rowstart[n], end = rowstart[n + 1];

  float adn;
  if (MODE == 1) adn = adst[n * H + h];
  else { float2 t2 = ((const float2*)adst)[n * H + h]; adn = t2.x + t2.y; }

  float acc[8] = {};
  float wsum = 0.f;

  for (int c0 = beg; c0 < end; c0 += 64) {
    int len = end - c0; if (len > 64) len = 64;
    int ev = (lane < len) ? csr_src[c0 + lane] : 0;
    int j = 0;
    for (; j + 1 < len; j += 2) {
      int s0 = __shfl(ev, j), s1 = __shfl(ev, j + 1);
      float v0, v1;
      if (MODE == 1) { v0 = asrc[s0 * H + h]; v1 = asrc[s1 * H + h]; }
      else {
        float2 p0 = ((const float2*)asrc)[s0 * H + h];
        float2 p1 = ((const float2*)asrc)[s1 * H + h];
        v0 = p0.x + p0.y; v1 = p1.x + p1.y;
      }
      u16x8 a0 = ((const u16x8*)xp)[(size_t)s0 * 64 + lane];
      u16x8 a1 = ((const u16x8*)xp)[(size_t)s1 * 64 + lane];
      v0 += adn; v1 += adn;
      v0 = (v0 > 0.f) ? v0 : 0.2f * v0;
      v1 = (v1 > 0.f) ? v1 : 0.2f * v1;
      float w0 = __expf(v0), w1 = __expf(v1);
#pragma unroll
      for (int k = 0; k < 8; ++k)
        acc[k] += w0 * bf2f(a0[k]) + w1 * bf2f(a1[k]);
      wsum += w0 + w1;
    }
    if (j < len) {
      int s0 = __shfl(ev, j);
      float v0;
      if (MODE == 1) v0 = asrc[s0 * H + h];
      else { float2 p0 = ((const float2*)asrc)[s0 * H + h]; v0 = p0.x + p0.y; }
      u16x8 a0 = ((const u16x8*)xp)[(size_t)s0 * 64 + lane];
      v0 += adn;
      v0 = (v0 > 0.f) ? v0 : 0.2f * v0;
      float w0 = __expf(v0);
#pragma unroll
      for (int k = 0; k < 8; ++k) acc[k] += w0 * bf2f(a0[k]);
      wsum += w0;
    }
  }
  float rdn = 1.0f / (wsum + 1e-16f);
#pragma unroll
  for (int k = 0; k < 8; ++k) acc[k] *= rdn;

  if (MODE == 1) {
    int c = lane * 8;
    u16x8 rr;
#pragma unroll
    for (int k = 0; k < 8; ++k) {
      float v = acc[k] + bias[c + k];
      v = (v > 0.f) ? v : expm1f(v);
      rr[k] = f2bf(v);
    }
    ((u16x8*)hout)[(size_t)n * 64 + lane] = rr;
  } else {
    // head-mean: channel c'=(lane&15)*8+k lives on lanes {l, l^16, l^32, l^48}
#pragma unroll
    for (int k = 0; k < 8; ++k) {
      float v = acc[k];
      v += __shfl_xor(v, 16);
      v += __shfl_xor(v, 32);
      acc[k] = v * 0.25f + bias[(lane & 15) * 8 + k];
    }
    if (lane < 16) {       // scalar stores: out2 = out+1 is only 4B-aligned
      int cb = lane * 8;
#pragma unroll
      for (int k = 0; k < 8; ++k) out2[(size_t)n * NC2 + cb + k] = acc[k];
    }
    // fused CE: lanes 0..15 hold the 128 logits (copies in upper 48 lanes)
    float mx = acc[0];
#pragma unroll
    for (int k = 1; k < 8; ++k) mx = fmaxf(mx, acc[k]);
#pragma unroll
    for (int o = 1; o < 16; o <<= 1) mx = fmaxf(mx, __shfl_xor(mx, o));
    float e = 0.f;
#pragma unroll
    for (int k = 0; k < 8; ++k) e += __expf(acc[k] - mx);
#pragma unroll
    for (int o = 1; o < 16; o <<= 1) e += __shfl_xor(e, o);
    int yv = y[n];
    float sel = acc[0];
#pragma unroll
    for (int k = 1; k < 8; ++k) sel = ((yv & 7) == k) ? acc[k] : sel;
    float vy = __shfl(sel, yv >> 3);
    if (lane == 0 && msk[n] != 0) {
      float ce = mx + logf(e) - vy;
      int slot = n & 127;
      atomicAdd(&acc2[slot], ce);
      atomicAdd(&acc2[128 + slot], 1.0f);
    }
  }
}

__global__ void k_final(const float* __restrict__ acc2, float* __restrict__ out0) {
  int tid = threadIdx.x;   // 128 threads
  float ce = acc2[tid], ct = acc2[128 + tid];
#pragma unroll
  for (int o = 32; o > 0; o >>= 1) { ce += __shfl_xor(ce, o); ct += __shfl_xor(ct, o); }
  __shared__ float s[4];
  if ((tid & 63) == 0) { s[(tid >> 6) * 2] = ce; s[(tid >> 6) * 2 + 1] = ct; }
  __syncthreads();
  if (tid == 0) out0[0] = (s[0] + s[2]) / (s[1] + s[3]);
}

extern "C" void kernel_launch(void* const* d_in, const int* in_sizes, int n_in,
                              void* d_out, int out_size, void* d_ws, size_t ws_size,
                              hipStream_t stream) {
  const float* x   = (const float*)d_in[0];
  const int*   ei  = (const int*)d_in[1];
  const int*   y   = (const int*)d_in[2];
  const int*   msk = (const int*)d_in[3];
  const float* W1  = (const float*)d_in[4];
  const float* as1 = (const float*)d_in[5];
  const float* ad1 = (const float*)d_in[6];
  const float* b1  = (const float*)d_in[7];
  const float* W2  = (const float*)d_in[8];
  const float* as2 = (const float*)d_in[9];
  const float* ad2 = (const float*)d_in[10];
  const float* b2  = (const float*)d_in[11];
  float* out = (float*)d_out;

  int N = in_sizes[0] / D_IN;   // 20000
  int E = in_sizes[1] / 2;      // 100000
  int Etot = E + N;             // 120000 (self-loops appended)

  float* ws = (float*)d_ws;
  size_t NF = (size_t)N * HC;
  float* asr1 = ws;                       // N*8  (plain-written in GEMM1)
  float* adt1 = asr1 + (size_t)N * NH1;   // N*8
  float* asr2 = adt1 + (size_t)N * NH1;   // N*8  (partials, plain-written GEMM2)
  float* adt2 = asr2 + (size_t)N * 2 * NH2; // N*8
  // ---- zero-init region: acc2, cnt, cursor (contiguous) ----
  float* acc2 = adt2 + (size_t)N * 2 * NH2; // 256
  int*   cnt    = (int*)(acc2 + 256);     // N
  int*   cursor = cnt + N;                // N
  size_t zero_bytes = (256 + 2 * (size_t)N) * sizeof(float);
  // ---- fully-written region ----
  int*   rowstart = cursor + N;           // N+1
  int*   csr_src  = rowstart + N + 1;     // Etot
  ushort* xpbf = (ushort*)((((uintptr_t)(csr_src + Etot)) + 15) & ~(uintptr_t)15);
  ushort* Abf = xpbf + NF;                // N*512
  ushort* Wt1 = Abf + NF;                 // 512*512
  ushort* Wt2 = Wt1 + (size_t)D_IN * HC;  // 512*512

  hipMemsetAsync(acc2, 0, zero_bytes, stream);

  // all casts (x, W1^T, W2^T) in one launch
  int n4x = (int)(NF / 4);
  int cast_total = n4x + 2 * D_IN * HC;
  k_cast_all<<<(cast_total + 255) / 256, 256, 0, stream>>>(x, Abf, W1, W2, Wt1, Wt2, n4x);

  // CSR build (shared by both layers)
  k_hist<<<(Etot + 255) / 256, 256, 0, stream>>>(ei, E, Etot, cnt);
  k_scan<<<1, 1024, 0, stream>>>(cnt, rowstart, N);
  k_scatter<<<(Etot + 255) / 256, 256, 0, stream>>>(ei, E, Etot, rowstart, cursor, csr_src);

  dim3 ggrid(HC / BN, (N + BM - 1) / BM);   // 4 x 157
  int aggblocks = (N + 3) / 4;              // 4 nodes (waves) per block

  // ---- layer 1 ----
  k_gemm_bf16<NH1><<<ggrid, 256, 0, stream>>>(Abf, Wt1, xpbf, as1, ad1, asr1, adt1, N);
  k_agg<NH1, 1><<<aggblocks, 256, 0, stream>>>(rowstart, csr_src, asr1, adt1, xpbf, Abf,
                                               nullptr, b1, nullptr, nullptr, nullptr, N);

  // ---- layer 2 ----
  k_gemm_bf16<NH2><<<ggrid, 256, 0, stream>>>(Abf, Wt2, xpbf, as2, ad2, asr2, adt2, N);
  k_agg<NH2, 2><<<aggblocks, 256, 0, stream>>>(rowstart, csr_src, asr2, adt2, xpbf, nullptr,
                                               out + 1, b2, y, msk, acc2, N);

  // ---- epilogue: loss ----
  k_final<<<1, 128, 0, stream>>>(acc2, out);
}

// Round 2
// 294.382 us; speedup vs baseline: 1.0054x; 1.0054x over previous
//
#include <hip/hip_runtime.h>
#include <cmath>

#define D_IN 512
#define HC   512   // H1*C1 == H2*C2 == D_IN
#define NH1  8
#define NC1  64
#define NH2  4
#define NC2  128
#define BM 128
#define BN 128

typedef __attribute__((ext_vector_type(8))) short short8;
typedef __attribute__((ext_vector_type(8))) unsigned short u16x8;
typedef __attribute__((ext_vector_type(4))) float f32x4;

__device__ inline ushort f2bf(float f) {
  unsigned u = __float_as_uint(f);
  return (ushort)((u + 0x7FFFu + ((u >> 16) & 1u)) >> 16);
}
__device__ inline float bf2f(ushort b) { return __uint_as_float(((unsigned)b) << 16); }

// ---------- all input casts + degree histogram in ONE launch (R15) ---------
__global__ void k_pre(const float* __restrict__ x, ushort* __restrict__ Abf,
                      const float* __restrict__ W1, const float* __restrict__ W2,
                      ushort* __restrict__ Wt1, ushort* __restrict__ Wt2, int n4x,
                      const int* __restrict__ ei, int E, int Etot,
                      int* __restrict__ cnt) {
  const int KN = D_IN * HC;
  int i = blockIdx.x * blockDim.x + threadIdx.x;
  if (i < n4x) {
    float4 v = ((const float4*)x)[i];
    ushort4 r = { f2bf(v.x), f2bf(v.y), f2bf(v.z), f2bf(v.w) };
    ((ushort4*)Abf)[i] = r;
  } else if (i < n4x + 2 * KN) {
    int idx = i - n4x;
    const float* W = (idx < KN) ? W1 : W2;
    ushort* Wt = (idx < KN) ? Wt1 : Wt2;
    int j = (idx < KN) ? idx : idx - KN;
    int n = j / D_IN, k = j - n * D_IN;
    Wt[j] = f2bf(W[(size_t)k * HC + n]);
  } else {
    int e = i - n4x - 2 * KN;
    if (e >= Etot) return;
    int d = (e < E) ? ei[E + e] : e - E;
    atomicAdd(&cnt[d], 1);
  }
}

// ---------- bf16 MFMA GEMM, 3-buffer depth-2 pipeline, BK=32 (R15) ---------
// R14's 2-phase was depth-1: the vmcnt(4) waited on loads issued only one
// compute-phase (~400cy) earlier vs ~900cy HBM latency -> per-step stall.
// R15: 3 LDS buffers (48KB, still >= 3 blocks/CU vs 2.45 resident), stage
// tile it+2 each iter, wait vmcnt(8) (12 in flight, oldest tile drained) ->
// ~2 compute-phases (~800cy+) of latency hidden. Tail peels vmcnt(4)/(0).
// s_barrier is IntrNoMem in LLVM: every barrier is sandwiched with
// asm ""::: "memory" fences so ds_reads / global_load_lds can't be hoisted
// across it. NOTE: buffer staged at iter it == buffer computed at it-1
// ((it+2)%3 == (it-1)%3), so the trailing barrier is load-bearing.
// Fragment layout unchanged (conflict-free, verified R9). XCD-aware
// bijective swizzle (m204): same-XCD blocks get consecutive wg -> the 4
// n-blocks sharing an A row-panel are L2-local.
// Att epilogue unchanged: plain stores only. H=8 (C=64): one slot/(row,h).
// H=4 (C=128): two partial slots [(row*4+h)*2+sub], sub=col64-idx.
template<int H>
__global__ void k_gemm_bf16(const ushort* __restrict__ A, const ushort* __restrict__ Bt,
                            ushort* __restrict__ Cbf,
                            const float* __restrict__ att_s, const float* __restrict__ att_d,
                            float* __restrict__ asrc, float* __restrict__ adst, int M) {
  constexpr int C = HC / H;
  __shared__ __align__(16) ushort As[3 * 4096];   // 3 bufs x (128 rows x 32 cols)
  __shared__ __align__(16) ushort Bs[3 * 4096];
  int t = threadIdx.x;

  // bijective XCD swizzle (nwg=628, 8 XCDs): contiguous wg-chunk per XCD
  int nwg = gridDim.x * gridDim.y;
  int lin = blockIdx.y * gridDim.x + blockIdx.x;
  int q = nwg >> 3, r = nwg & 7;
  int xcd = lin & 7, pos = lin >> 3;
  int wg = (xcd < r ? xcd * (q + 1) : r * (q + 1) + (xcd - r) * q) + pos;
  int m0 = (wg >> 2) * BM;        // gridDim.x == 4
  int n0 = (wg & 3) * BN;

  int wave = t >> 6, lane = t & 63;
  int ln = lane & 15, qd = lane >> 4;
  int wm = (wave >> 1) * 64, wn = (wave & 1) * 64;

  f32x4 acc[4][4] = {};

  int g = t >> 6, ct = (t >> 4) & 3, lt = t & 15;
  int rA0 = m0 + g * 16 + lt;      if (rA0 > M - 1) rA0 = M - 1;
  int rA1 = m0 + 64 + g * 16 + lt; if (rA1 > M - 1) rA1 = M - 1;
  const ushort* gA0 = A + (size_t)rA0 * D_IN + ct * 8;
  const ushort* gA1 = A + (size_t)rA1 * D_IN + ct * 8;
  const ushort* gB0 = Bt + (size_t)(n0 + g * 16 + lt) * D_IN + ct * 8;
  const ushort* gB1 = Bt + (size_t)(n0 + 64 + g * 16 + lt) * D_IN + ct * 8;

#define STAGE(buf, ko)                                                          \
  do {                                                                          \
    int lo_ = (buf) * 4096;                                                     \
    __builtin_amdgcn_global_load_lds(                                           \
        (const __attribute__((address_space(1))) void*)(gA0 + (ko)),            \
        (__attribute__((address_space(3))) void*)(As + lo_ + t * 8), 16, 0, 0); \
    __builtin_amdgcn_global_load_lds(                                           \
        (const __attribute__((address_space(1))) void*)(gA1 + (ko)),            \
        (__attribute__((address_space(3))) void*)(As + lo_ + 2048 + t * 8), 16, 0, 0); \
    __builtin_amdgcn_global_load_lds(                                           \
        (const __attribute__((address_space(1))) void*)(gB0 + (ko)),            \
        (__attribute__((address_space(3))) void*)(Bs + lo_ + t * 8), 16, 0, 0); \
    __builtin_amdgcn_global_load_lds(                                           \
        (const __attribute__((address_space(1))) void*)(gB1 + (ko)),            \
        (__attribute__((address_space(3))) void*)(Bs + lo_ + 2048 + t * 8), 16, 0, 0); \
  } while (0)

#define COMPUTE(BUF)                                                            \
  do {                                                                          \
    int lo = (BUF) * 4096;                                                      \
    short8 a[4], bb[4];                                                         \
    _Pragma("unroll") for (int i = 0; i < 4; ++i)                               \
      a[i] = *(const short8*)&As[lo + (((wave >> 1) * 4 + i) * 4 + qd) * 128 + ln * 8]; \
    _Pragma("unroll") for (int j = 0; j < 4; ++j)                               \
      bb[j] = *(const short8*)&Bs[lo + (((wave & 1) * 4 + j) * 4 + qd) * 128 + ln * 8]; \
    _Pragma("unroll") for (int i = 0; i < 4; ++i)                               \
      _Pragma("unroll") for (int j = 0; j < 4; ++j)                             \
        acc[i][j] = __builtin_amdgcn_mfma_f32_16x16x32_bf16(a[i], bb[j], acc[i][j], 0, 0, 0); \
  } while (0)

  STAGE(0, 0);
  STAGE(1, 32);
  int cb = 0;
  for (int it = 0; it < 14; ++it) {
    int sb = (it + 2) % 3;
    STAGE(sb, (it + 2) * 32);
    asm volatile("s_waitcnt vmcnt(8)" ::: "memory");   // tile it landed
    __builtin_amdgcn_s_barrier();
    asm volatile("" ::: "memory");
    COMPUTE(cb);
    asm volatile("" ::: "memory");
    __builtin_amdgcn_s_barrier();                      // reads done before overwrite
    asm volatile("" ::: "memory");
    cb = (cb == 2) ? 0 : cb + 1;
  }
  // tile 14 (buf 2)
  asm volatile("s_waitcnt vmcnt(4)" ::: "memory");
  __builtin_amdgcn_s_barrier();
  asm volatile("" ::: "memory");
  COMPUTE(2);
  // tile 15 (buf 0)
  asm volatile("s_waitcnt vmcnt(0)" ::: "memory");
  __builtin_amdgcn_s_barrier();
  asm volatile("" ::: "memory");
  COMPUTE(0);
#undef STAGE
#undef COMPUTE

  // ---- C store (C/D layout: col = ln, row = qd*4 + reg) ----
#pragma unroll
  for (int i = 0; i < 4; ++i) {
#pragma unroll
    for (int reg = 0; reg < 4; ++reg) {
      int row = m0 + wm + i * 16 + qd * 4 + reg;
      if (row >= M) continue;
#pragma unroll
      for (int j = 0; j < 4; ++j)
        Cbf[(size_t)row * HC + n0 + wn + j * 16 + ln] = f2bf(acc[i][j][reg]);
    }
  }

  // ---- fused attention scores (plain stores only) ----
  int colbase = n0 + wn;         // multiple of 64
  int h = colbase / C;
  float sa[4], da[4];
#pragma unroll
  for (int j = 0; j < 4; ++j) {
    int c = (colbase % C) + j * 16 + ln;
    sa[j] = att_s[h * C + c];
    da[j] = att_d[h * C + c];
  }
#pragma unroll
  for (int i = 0; i < 4; ++i) {
#pragma unroll
    for (int reg = 0; reg < 4; ++reg) {
      float ps = acc[i][0][reg] * sa[0] + acc[i][1][reg] * sa[1]
               + acc[i][2][reg] * sa[2] + acc[i][3][reg] * sa[3];
      float pd = acc[i][0][reg] * da[0] + acc[i][1][reg] * da[1]
               + acc[i][2][reg] * da[2] + acc[i][3][reg] * da[3];
#pragma unroll
      for (int o = 1; o < 16; o <<= 1) { ps += __shfl_xor(ps, o); pd += __shfl_xor(pd, o); }
      int row = m0 + wm + i * 16 + qd * 4 + reg;
      if (ln == 0 && row < M) {
        if (C == 64) {
          asrc[row * H + h] = ps; adst[row * H + h] = pd;
        } else {
          int sub = (colbase >> 6) & 1;
          asrc[(row * H + h) * 2 + sub] = ps;
          adst[(row * H + h) * 2 + sub] = pd;
        }
      }
    }
  }
}

// ---------------- CSR build ------------------------------------------------
// single-block scan, thread-serial + shuffle (2 barriers total)
__global__ void k_scan(const int* __restrict__ cnt, int* __restrict__ rowstart, int N) {
  int tid = threadIdx.x;                 // 1024
  int T = (N + 1023) / 1024;
  int base = tid * T;
  int sum = 0;
  for (int i = 0; i < T; ++i) { int j = base + i; if (j < N) sum += cnt[j]; }
  int lane = tid & 63, w = tid >> 6;
  int v = sum;
#pragma unroll
  for (int off = 1; off < 64; off <<= 1) {
    int u = __shfl_up(v, off);
    if (lane >= off) v += u;
  }
  __shared__ int wsum[16];
  if (lane == 63) wsum[w] = v;
  __syncthreads();
  if (tid < 16) {
    int tv = wsum[tid];
#pragma unroll
    for (int off = 1; off < 16; off <<= 1) {
      int u = __shfl_up(tv, off);
      if (tid >= off) tv += u;
    }
    wsum[tid] = tv;
  }
  __syncthreads();
  int wave_prefix = (w == 0) ? 0 : wsum[w - 1];
  int run = wave_prefix + v - sum;       // exclusive prefix for this thread
  for (int i = 0; i < T; ++i) {
    int j = base + i;
    if (j < N) { rowstart[j] = run; run += cnt[j]; }
  }
  if (tid == 1023) rowstart[N] = run;
}

__global__ void k_scatter(const int* __restrict__ ei, int E, int Etot,
                          const int* __restrict__ rowstart, int* __restrict__ cursor,
                          int* __restrict__ csr_src) {
  int e = blockIdx.x * blockDim.x + threadIdx.x;
  if (e >= Etot) return;
  int s = (e < E) ? ei[e] : e - E;
  int d = (e < E) ? ei[E + e] : e - E;
  int pos = atomicAdd(&cursor[d], 1);
  csr_src[rowstart[d] + pos] = s;
}

// -------- gather aggregation, ONE WAVE PER NODE (R14) ----------------------
// wave-per-node, 4 nodes per 256-thr block, no LDS/barriers — edge ids
// loaded 64-wide and broadcast via __shfl; 16B/lane gathers. 2-way edge
// unroll for MLP. No max-subtraction (scores O(1), fp32-safe).
// MODE 1 (H=8): scores at [x*H+h]; hout = bf16(elu(sum/den + b)).
// MODE 2 (H=4): scores are 2 partials at [(x*H+h)*2+{0,1}];
//   head-mean via shfl_xor(16,32) fold; fused CE via 16-lane butterflies.
template<int H, int MODE>
__global__ void k_agg(const int* __restrict__ rowstart, const int* __restrict__ csr_src,
                      const float* __restrict__ asrc, const float* __restrict__ adst,
                      const ushort* __restrict__ xp, ushort* __restrict__ hout,
                      float* __restrict__ out2, const float* __restrict__ bias,
                      const int* __restrict__ y, const int* __restrict__ msk,
                      float* __restrict__ acc2, int N) {
  constexpr int C = HC / H;
  int wv = threadIdx.x >> 6, lane = threadIdx.x & 63;
  int n = blockIdx.x * 4 + wv;
  if (n >= N) return;                         // wave-uniform
  int h = (MODE == 1) ? (lane >> 3) : (lane >> 4);   // 8 chans/lane
  int beg = rowstart[n], end = rowstart[n + 1];

  float adn;
  if (MODE == 1) adn = adst[n * H + h];
  else { float2 t2 = ((const float2*)adst)[n * H + h]; adn = t2.x + t2.y; }

  float acc[8] = {};
  float wsum = 0.f;

  for (int c0 = beg; c0 < end; c0 += 64) {
    int len = end - c0; if (len > 64) len = 64;
    int ev = (lane < len) ? csr_src[c0 + lane] : 0;
    int j = 0;
    for (; j + 1 < len; j += 2) {
      int s0 = __shfl(ev, j), s1 = __shfl(ev, j + 1);
      float v0, v1;
      if (MODE == 1) { v0 = asrc[s0 * H + h]; v1 = asrc[s1 * H + h]; }
      else {
        float2 p0 = ((const float2*)asrc)[s0 * H + h];
        float2 p1 = ((const float2*)asrc)[s1 * H + h];
        v0 = p0.x + p0.y; v1 = p1.x + p1.y;
      }
      u16x8 a0 = ((const u16x8*)xp)[(size_t)s0 * 64 + lane];
      u16x8 a1 = ((const u16x8*)xp)[(size_t)s1 * 64 + lane];
      v0 += adn; v1 += adn;
      v0 = (v0 > 0.f) ? v0 : 0.2f * v0;
      v1 = (v1 > 0.f) ? v1 : 0.2f * v1;
      float w0 = __expf(v0), w1 = __expf(v1);
#pragma unroll
      for (int k = 0; k < 8; ++k)
        acc[k] += w0 * bf2f(a0[k]) + w1 * bf2f(a1[k]);
      wsum += w0 + w1;
    }
    if (j < len) {
      int s0 = __shfl(ev, j);
      float v0;
      if (MODE == 1) v0 = asrc[s0 * H + h];
      else { float2 p0 = ((const float2*)asrc)[s0 * H + h]; v0 = p0.x + p0.y; }
      u16x8 a0 = ((const u16x8*)xp)[(size_t)s0 * 64 + lane];
      v0 += adn;
      v0 = (v0 > 0.f) ? v0 : 0.2f * v0;
      float w0 = __expf(v0);
#pragma unroll
      for (int k = 0; k < 8; ++k) acc[k] += w0 * bf2f(a0[k]);
      wsum += w0;
    }
  }
  float rdn = 1.0f / (wsum + 1e-16f);
#pragma unroll
  for (int k = 0; k < 8; ++k) acc[k] *= rdn;

  if (MODE == 1) {
    int c = lane * 8;
    u16x8 rr;
#pragma unroll
    for (int k = 0; k < 8; ++k) {
      float v = acc[k] + bias[c + k];
      v = (v > 0.f) ? v : expm1f(v);
      rr[k] = f2bf(v);
    }
    ((u16x8*)hout)[(size_t)n * 64 + lane] = rr;
  } else {
    // head-mean: channel c'=(lane&15)*8+k lives on lanes {l, l^16, l^32, l^48}
#pragma unroll
    for (int k = 0; k < 8; ++k) {
      float v = acc[k];
      v += __shfl_xor(v, 16);
      v += __shfl_xor(v, 32);
      acc[k] = v * 0.25f + bias[(lane & 15) * 8 + k];
    }
    if (lane < 16) {       // scalar stores: out2 = out+1 is only 4B-aligned
      int cb = lane * 8;
#pragma unroll
      for (int k = 0; k < 8; ++k) out2[(size_t)n * NC2 + cb + k] = acc[k];
    }
    // fused CE: lanes 0..15 hold the 128 logits (copies in upper 48 lanes)
    float mx = acc[0];
#pragma unroll
    for (int k = 1; k < 8; ++k) mx = fmaxf(mx, acc[k]);
#pragma unroll
    for (int o = 1; o < 16; o <<= 1) mx = fmaxf(mx, __shfl_xor(mx, o));
    float e = 0.f;
#pragma unroll
    for (int k = 0; k < 8; ++k) e += __expf(acc[k] - mx);
#pragma unroll
    for (int o = 1; o < 16; o <<= 1) e += __shfl_xor(e, o);
    int yv = y[n];
    float sel = acc[0];
#pragma unroll
    for (int k = 1; k < 8; ++k) sel = ((yv & 7) == k) ? acc[k] : sel;
    float vy = __shfl(sel, yv >> 3);
    if (lane == 0 && msk[n] != 0) {
      float ce = mx + logf(e) - vy;
      int slot = n & 127;
      atomicAdd(&acc2[slot], ce);
      atomicAdd(&acc2[128 + slot], 1.0f);
    }
  }
}

__global__ void k_final(const float* __restrict__ acc2, float* __restrict__ out0) {
  int tid = threadIdx.x;   // 128 threads
  float ce = acc2[tid], ct = acc2[128 + tid];
#pragma unroll
  for (int o = 32; o > 0; o >>= 1) { ce += __shfl_xor(ce, o); ct += __shfl_xor(ct, o); }
  __shared__ float s[4];
  if ((tid & 63) == 0) { s[(tid >> 6) * 2] = ce; s[(tid >> 6) * 2 + 1] = ct; }
  __syncthreads();
  if (tid == 0) out0[0] = (s[0] + s[2]) / (s[1] + s[3]);
}

extern "C" void kernel_launch(void* const* d_in, const int* in_sizes, int n_in,
                              void* d_out, int out_size, void* d_ws, size_t ws_size,
                              hipStream_t stream) {
  const float* x   = (const float*)d_in[0];
  const int*   ei  = (const int*)d_in[1];
  const int*   y   = (const int*)d_in[2];
  const int*   msk = (const int*)d_in[3];
  const float* W1  = (const float*)d_in[4];
  const float* as1 = (const float*)d_in[5];
  const float* ad1 = (const float*)d_in[6];
  const float* b1  = (const float*)d_in[7];
  const float* W2  = (const float*)d_in[8];
  const float* as2 = (const float*)d_in[9];
  const float* ad2 = (const float*)d_in[10];
  const float* b2  = (const float*)d_in[11];
  float* out = (float*)d_out;

  int N = in_sizes[0] / D_IN;   // 20000
  int E = in_sizes[1] / 2;      // 100000
  int Etot = E + N;             // 120000 (self-loops appended)

  float* ws = (float*)d_ws;
  size_t NF = (size_t)N * HC;
  float* asr1 = ws;                       // N*8  (plain-written in GEMM1)
  float* adt1 = asr1 + (size_t)N * NH1;   // N*8
  float* asr2 = adt1 + (size_t)N * NH1;   // N*8  (partials, plain-written GEMM2)
  float* adt2 = asr2 + (size_t)N * 2 * NH2; // N*8
  // ---- zero-init region: acc2, cnt, cursor (contiguous) ----
  float* acc2 = adt2 + (size_t)N * 2 * NH2; // 256
  int*   cnt    = (int*)(acc2 + 256);     // N
  int*   cursor = cnt + N;                // N
  size_t zero_bytes = (256 + 2 * (size_t)N) * sizeof(float);
  // ---- fully-written region ----
  int*   rowstart = cursor + N;           // N+1
  int*   csr_src  = rowstart + N + 1;     // Etot
  ushort* xpbf = (ushort*)((((uintptr_t)(csr_src + Etot)) + 15) & ~(uintptr_t)15);
  ushort* Abf = xpbf + NF;                // N*512
  ushort* Wt1 = Abf + NF;                 // 512*512
  ushort* Wt2 = Wt1 + (size_t)D_IN * HC;  // 512*512

  hipMemsetAsync(acc2, 0, zero_bytes, stream);

  // casts (x, W1^T, W2^T) + degree histogram in one launch
  int n4x = (int)(NF / 4);
  int pre_total = n4x + 2 * D_IN * HC + Etot;
  k_pre<<<(pre_total + 255) / 256, 256, 0, stream>>>(x, Abf, W1, W2, Wt1, Wt2, n4x,
                                                     ei, E, Etot, cnt);

  // CSR build (shared by both layers)
  k_scan<<<1, 1024, 0, stream>>>(cnt, rowstart, N);
  k_scatter<<<(Etot + 255) / 256, 256, 0, stream>>>(ei, E, Etot, rowstart, cursor, csr_src);

  dim3 ggrid(HC / BN, (N + BM - 1) / BM);   // 4 x 157
  int aggblocks = (N + 3) / 4;              // 4 nodes (waves) per block

  // ---- layer 1 ----
  k_gemm_bf16<NH1><<<ggrid, 256, 0, stream>>>(Abf, Wt1, xpbf, as1, ad1, asr1, adt1, N);
  k_agg<NH1, 1><<<aggblocks, 256, 0, stream>>>(rowstart, csr_src, asr1, adt1, xpbf, Abf,
                                               nullptr, b1, nullptr, nullptr, nullptr, N);

  // ---- layer 2 ----
  k_gemm_bf16<NH2><<<ggrid, 256, 0, stream>>>(Abf, Wt2, xpbf, as2, ad2, asr2, adt2, N);
  k_agg<NH2, 2><<<aggblocks, 256, 0, stream>>>(rowstart, csr_src, asr2, adt2, xpbf, nullptr,
                                               out + 1, b2, y, msk, acc2, N);

  // ---- epilogue: loss ----
  k_final<<<1, 128, 0, stream>>>(acc2, out);
}